// Round 4
// baseline (155.485 us; speedup 1.0000x reference)
//
#include <hip/hip_runtime.h>

typedef unsigned int u32;
typedef unsigned char u8;
typedef unsigned long long u64;

// Problem constants
#define DIMS   10000
#define LEVELS 100
#define SSIZE  617
#define SPAD   624        // padded s (multiple of 2; rows 617..623 are zero)
#define NCLS   26
#define BATCH  32
#define WORDS  313        // ceil(10000/32) real sign-bit words per row
#define WPITCH 320        // padded word pitch (idb, lvb, enc); words 313..319 = 0
#define DPITCH 10240      // WPITCH*32 byte-count pitch per (slot,b)
#define NTILE  5          // d-tiles of 64 words (2048 dims)
#define MAXNCH 104        // s-chunks: 624/104 = 6 per slot

// ws layout (bytes)
#define OFF_OFFB 0x000000u  // 624*32*4   =  79,872
#define OFF_IDB  0x020000u  // 624*320*4  = 798,720
#define OFF_LVB  0x100000u  // 100*320*4  = 128,000
#define OFF_ENC  0x120000u  // 32*320*4   =  40,960
#define OFF_P8   0x140000u  // nch*32*10240
#define SLOT_BYTES ((size_t)BATCH * DPITCH)   // 327,680

// k_pack flat work ranges
#define N_ID (SPAD * WPITCH)     // 199,680 words
#define N_LV (LEVELS * WPITCH)   //  32,000 words
#define N_X  (SPAD * BATCH)      //  19,968 offsets
#define N_O  (BATCH * NCLS)      //     832 out zeros
#define PACK_THREADS (N_ID + N_LV + N_X + N_O)
#define PACK_BLOCKS ((PACK_THREADS + 255) / 256)

// ---------------------------------------------------------------------------
// K1: one thread = one 32-dim sign word (8 x float4, MSB extract), covering
// both id_w and level_w (zero-padded rows/words); plus x -> quantized LDS row
// byte offsets (transposed [s][b], pad s -> zero row 100); plus zero d_out.
// ---------------------------------------------------------------------------
__global__ __launch_bounds__(256) void k_pack(const float* __restrict__ x,
                                              const float* __restrict__ idw,
                                              const float* __restrict__ lvw,
                                              u32* __restrict__ idb,
                                              u32* __restrict__ lvb,
                                              u32* __restrict__ offb,
                                              float* __restrict__ out)
{
    int tid = blockIdx.x * 256 + threadIdx.x;
    if (tid < N_ID + N_LV) {
        const bool isLvl = tid >= N_ID;
        int t = isLvl ? tid - N_ID : tid;
        int r = t / WPITCH;
        int w = t - r * WPITCH;
        const float* src = isLvl ? lvw : idw;
        const int rows = isLvl ? LEVELS : SSIZE;
        u32 bits = 0;
        if (r < rows && w < WORDS) {
            const float* p = src + (size_t)r * DIMS + w * 32;
#pragma unroll
            for (int q = 0; q < 8; ++q) {
                int d = w * 32 + q * 4;
                if (d + 3 < DIMS) {             // word 312: upper quads skip
                    float4 f = *(const float4*)(p + q * 4);
                    u32 nb =  (__builtin_bit_cast(u32, f.x) >> 31)
                           | ((__builtin_bit_cast(u32, f.y) >> 31) << 1)
                           | ((__builtin_bit_cast(u32, f.z) >> 31) << 2)
                           | ((__builtin_bit_cast(u32, f.w) >> 31) << 3);
                    bits |= nb << (4 * q);
                }
            }
        }
        (isLvl ? lvb : idb)[(size_t)r * WPITCH + w] = bits;
        return;
    }
    int t2 = tid - (N_ID + N_LV);
    if (t2 < N_X) {
        int s = t2 >> 5, b = t2 & 31;
        u32 off = LEVELS * 256u;               // pad s -> zero tile row 100
        if (s < SSIZE) {
            float v = x[b * SSIZE + s];
            float r = rintf(v * (float)(LEVELS - 1));  // RTE = jnp.round
            int q = (int)r;
            q = q < 0 ? 0 : (q > LEVELS - 1 ? LEVELS - 1 : q);
            off = (u32)q * 256u;               // LDS row byte offset
        }
        offb[s * BATCH + b] = off;
        return;
    }
    int t3 = t2 - N_X;
    if (t3 < N_O) out[t3] = 0.0f;
}

// ---------------------------------------------------------------------------
// K2: bit-sliced bind+count. Block = 2048 dims (64 words, lane=word) x 32 b
// (4 waves x 8 b). Level-bit tile (101 rows x 256 B, row 100 = zeros) in LDS.
// Per s-pair per b: 2 ds_read_b32 + XOR + full-adder + ripple into 5 carry
// planes (chunk <= 62 -> no overflow). End: nibble-spread planes -> u8 counts.
// Pad words (313..319) are zero in both idb and lvb -> contribute 0.
// ---------------------------------------------------------------------------
__global__ __launch_bounds__(256) void k_bind(const u32* __restrict__ idb,
                                              const u32* __restrict__ lvb,
                                              const u32* __restrict__ offb,
                                              u32* __restrict__ part,
                                              int chunk)
{
    __shared__ u32 tile[(LEVELS + 1) * 64];    // 25.9 KB
    const int W0 = blockIdx.x * 64;
    const int slot = blockIdx.y;
    const int tid = threadIdx.x;

    for (int t = tid; t < (LEVELS + 1) * 64; t += 256) {
        int r = t >> 6, w = t & 63;
        tile[t] = (r < LEVELS) ? lvb[(size_t)r * WPITCH + W0 + w] : 0;
    }
    __syncthreads();

    const int lane = tid & 63;
    const int B0 = __builtin_amdgcn_readfirstlane((tid >> 6) * 8);
    const int wq = W0 + lane;                  // < 320, always in range
    const int sBeg = slot * chunk;
    const int sEnd = min(SPAD, sBeg + chunk);  // even span

    u32 ones[8], c0[8], c1[8], c2[8], c3[8], c4[8];
#pragma unroll
    for (int b = 0; b < 8; ++b) { ones[b]=0; c0[b]=0; c1[b]=0; c2[b]=0; c3[b]=0; c4[b]=0; }

    for (int s = sBeg; s < sEnd; s += 2) {
        u32 u1 = idb[(size_t)s * WPITCH + wq];
        u32 u2 = idb[(size_t)(s + 1) * WPITCH + wq];
        const u32* o1 = offb + s * BATCH + B0;   // wave-uniform -> s_load
        const u32* o2 = o1 + BATCH;
#pragma unroll
        for (int b = 0; b < 8; ++b) {
            u32 l1 = tile[(o1[b] >> 2) + lane];  // stride-1 -> conflict-free
            u32 l2 = tile[(o2[b] >> 2) + lane];
            u32 x1 = u1 ^ l1, x2 = u2 ^ l2;
            u32 t0 = x1 ^ x2;
            u32 sum = ones[b] ^ t0;
            u32 car = (x1 & x2) | (ones[b] & t0);
            ones[b] = sum;
            u32 t;
            t = c0[b] & car; c0[b] ^= car; car = t;
            t = c1[b] & car; c1[b] ^= car; car = t;
            t = c2[b] & car; c2[b] ^= car; car = t;
            t = c3[b] & car; c3[b] ^= car; car = t;
            c4[b] ^= car;                        // counts <= 62: no overflow
        }
    }

    // plane -> byte-count extraction: bit j of plane w -> byte j bit w.
#pragma unroll
    for (int b = 0; b < 8; ++b) {
        u32* dst = part + ((size_t)(slot * BATCH + B0 + b) * DPITCH + (size_t)wq * 32) / 4;
        u32 o[8];
#pragma unroll
        for (int g = 0; g < 8; ++g) {
            int sh = 4 * g;
            u32 n;
            n  =  (((ones[b] >> sh) & 0xFu) * 0x00204081u) & 0x01010101u;
            n |= ((((c0[b]  >> sh) & 0xFu) * 0x00204081u) & 0x01010101u) << 1;
            n |= ((((c1[b]  >> sh) & 0xFu) * 0x00204081u) & 0x01010101u) << 2;
            n |= ((((c2[b]  >> sh) & 0xFu) * 0x00204081u) & 0x01010101u) << 3;
            n |= ((((c3[b]  >> sh) & 0xFu) * 0x00204081u) & 0x01010101u) << 4;
            n |= ((((c4[b]  >> sh) & 0xFu) * 0x00204081u) & 0x01010101u) << 5;
            o[g] = n;
        }
        *(uint4*)(dst)     = make_uint4(o[0], o[1], o[2], o[3]);
        *(uint4*)(dst + 4) = make_uint4(o[4], o[5], o[6], o[7]);
    }
}

// ---------------------------------------------------------------------------
// K3: sum u8 slot partials per (b,d) with DWORD loads (4 dims/thread, packed
// u16-pair accumulate: max 104*62 = 6448 < 65536), threshold (enc=+1 <=>
// count<=308; multiset = 617-2*count is odd -> never 0), LDS nibble-pack.
// Block = (1024-dim chunk, b); grid (10, 32).
// ---------------------------------------------------------------------------
__global__ __launch_bounds__(256) void k_enc(const u32* __restrict__ part,
                                             u32* __restrict__ enc, int nch)
{
    const int b = blockIdx.y;
    const int q = blockIdx.x;
    const int t = threadIdx.x;
    const int dw = q * 256 + t;                 // dword index, < 2560
    const u32* p = part + (size_t)b * (DPITCH / 4) + dw;
    u32 a01 = 0, a23 = 0;
    for (int c = 0; c < nch; ++c) {
        u32 v = p[(size_t)c * BATCH * (DPITCH / 4)];
        a01 += v & 0x00FF00FFu;
        a23 += (v >> 8) & 0x00FF00FFu;
    }
    int s0 = (int)(a01 & 0xFFFFu), s2 = (int)(a01 >> 16);
    int s1 = (int)(a23 & 0xFFFFu), s3 = (int)(a23 >> 16);
    u32 nib = (u32)(s0 <= 308) | ((u32)(s1 <= 308) << 1)
            | ((u32)(s2 <= 308) << 2) | ((u32)(s3 <= 308) << 3);

    __shared__ u8 nibs[256];
    nibs[t] = (u8)nib;
    __syncthreads();
    if (t < 32) {
        u32 wbits = 0;
#pragma unroll
        for (int j = 0; j < 8; ++j)
            wbits |= (u32)(nibs[t * 8 + j] & 0xFu) << (4 * j);
        enc[b * WPITCH + q * 32 + t] = wbits;   // word w covers dims 32w..+31
    }
}

// ---------------------------------------------------------------------------
// K4: logit[b][c] = sum_d (+-1)*W[c,d]. Block per (c, 40-word group); thread
// = (b, seg); W row read once per group, enc from L1/L2. atomicAdd into the
// zeroed output (W == 0 in this problem, but computed faithfully).
// ---------------------------------------------------------------------------
__global__ __launch_bounds__(256) void k_logit(const u32* __restrict__ enc,
                                               const float* __restrict__ W,
                                               float* __restrict__ out)
{
    const int c = blockIdx.x;          // 26
    const int q = blockIdx.y;          // 8 groups of 40 words
    const int t = threadIdx.x;
    const int b = t & 31;
    const int seg = t >> 5;            // 0..7
    const u32* eb = enc + b * WPITCH;
    float acc = 0.0f;
    for (int w = q * 40; w < q * 40 + 40; ++w) {
        u32 ew = eb[w];
        int d = w * 32 + seg;
#pragma unroll
        for (int k = 0; k < 4; ++k, d += 8) {
            if (d < DIMS) {
                float wt = W[(size_t)c * DIMS + d];
                acc += ((ew >> (d & 31)) & 1u) ? wt : -wt;
            }
        }
    }
    acc += __shfl_xor(acc, 32);        // fold seg pairs within wave
    if ((t & 63) < 32) atomicAdd(out + b * NCLS + c, acc);
}

// ---------------------------------------------------------------------------
extern "C" void kernel_launch(void* const* d_in, const int* in_sizes, int n_in,
                              void* d_out, int out_size, void* d_ws, size_t ws_size,
                              hipStream_t stream)
{
    const float* x   = (const float*)d_in[0];  // (32, 617)
    const float* idw = (const float*)d_in[1];  // (617, 10000)
    const float* lvw = (const float*)d_in[2];  // (100, 10000)
    const float* W   = (const float*)d_in[3];  // (26, 10000)
    float* out = (float*)d_out;                // (32, 26)

    char* ws = (char*)d_ws;
    u32* offb = (u32*)(ws + OFF_OFFB);
    u32* idb  = (u32*)(ws + OFF_IDB);
    u32* lvb  = (u32*)(ws + OFF_LVB);
    u32* enc  = (u32*)(ws + OFF_ENC);
    u32* part = (u32*)(ws + OFF_P8);

    size_t avail = ws_size > OFF_P8 ? ws_size - OFF_P8 : 0;
    int nch = (int)(avail / SLOT_BYTES);
    if (nch > MAXNCH) nch = MAXNCH;
    if (nch < 1) nch = 1;
    int chunk = (SPAD + nch - 1) / nch;
    chunk = (chunk + 1) & ~1;                  // even (s-pairs)
    if (chunk > 62) chunk = 62;                // CSA capacity bound
    nch = (SPAD + chunk - 1) / chunk;          // default: chunk=6, nch=104

    k_pack<<<PACK_BLOCKS, 256, 0, stream>>>(x, idw, lvw, idb, lvb, offb, out);

    dim3 g2(NTILE, nch);                       // (5, 104) = 520 blocks
    k_bind<<<g2, 256, 0, stream>>>(idb, lvb, offb, part, chunk);

    dim3 g3(10, BATCH);                        // 320 blocks
    k_enc<<<g3, 256, 0, stream>>>(part, enc, nch);

    dim3 g4(NCLS, 8);                          // 208 blocks
    k_logit<<<g4, 256, 0, stream>>>(enc, W, out);
}

// Round 5
// 106.882 us; speedup vs baseline: 1.4547x; 1.4547x over previous
//
#include <hip/hip_runtime.h>

typedef unsigned int u32;
typedef unsigned char u8;
typedef unsigned long long u64;

// Problem constants
#define DIMS   10000
#define LEVELS 100
#define SSIZE  617
#define SPAD   624        // padded s (rows 617..623 zero in idb)
#define NCLS   26
#define BATCH  32
#define WORDS  313        // ceil(10000/32) real sign-bit words per row
#define WPITCH 320        // padded word pitch; words 313..319 = 0
#define DPITCH 10240      // byte-count pitch per (slot,b) = WPITCH*32
#define NTILE  5          // d-tiles of 64 words (2048 dims)
#define NCH    26         // s-chunks of 24 (624 = 26*24), counts <= 24 < 63
#define CHUNK  24

// ws layout (bytes)
#define OFF_OFFB 0x000000u  // 624*32*4   =  79,872
#define OFF_IDB  0x020000u  // 624*320*4  = 798,720
#define OFF_LVB  0x100000u  // 100*320*4  = 128,000
#define OFF_P8   0x140000u  // nch*32*10240 (26 slots = 8.3 MB)
#define SLOT_BYTES ((size_t)BATCH * DPITCH)   // 327,680

#define PK_ROWS (SPAD + LEVELS)   // 724: 0..616 id, 617..623 id-pad, 624..723 lvl

// ---------------------------------------------------------------------------
// K1: sign-pack, fully coalesced. Grid (10, 724): block (g, r) covers dims
// [1024g, 1024g+1024) of row r. Thread t loads ONE float4 (lane stride 16 B,
// perfect coalescing), makes a 4-bit nibble, LDS transpose, 32 threads emit
// words. Rows 617..623 and pad words 313..319 get zeros. Blocks with flat id
// < 78 also quantize x -> LDS-row byte offsets (transposed [s][b]) and zero
// d_out.
// ---------------------------------------------------------------------------
__global__ __launch_bounds__(256) void k_pack(const float* __restrict__ x,
                                              const float* __restrict__ idw,
                                              const float* __restrict__ lvw,
                                              u32* __restrict__ idb,
                                              u32* __restrict__ lvb,
                                              u32* __restrict__ offb,
                                              float* __restrict__ out)
{
    const int g = blockIdx.x;          // 0..9
    const int r = blockIdx.y;          // 0..723
    const int t = threadIdx.x;
    const bool isLvl = r >= SPAD;
    const int d0 = g * 1024 + 4 * t;

    u32 nib = 0;
    if (d0 + 3 < DIMS && (isLvl || r < SSIZE)) {
        const float* src = isLvl ? (lvw + (size_t)(r - SPAD) * DIMS)
                                 : (idw + (size_t)r * DIMS);
        float4 f = *(const float4*)(src + d0);
        nib =  (__builtin_bit_cast(u32, f.x) >> 31)
            | ((__builtin_bit_cast(u32, f.y) >> 31) << 1)
            | ((__builtin_bit_cast(u32, f.z) >> 31) << 2)
            | ((__builtin_bit_cast(u32, f.w) >> 31) << 3);
    }
    __shared__ u32 nibs[256];
    nibs[t] = nib;
    __syncthreads();
    if (t < 32) {
        u32 w = 0;
#pragma unroll
        for (int j = 0; j < 8; ++j) w |= nibs[t * 8 + j] << (4 * j);
        u32* dst = isLvl ? (lvb + (size_t)(r - SPAD) * WPITCH)
                         : (idb + (size_t)r * WPITCH);
        dst[g * 32 + t] = w;           // g*32+t spans 0..319 = WPITCH
    }

    // Side work on the first 78+ blocks (flat id B = r*10+g).
    const int B = r * 10 + g;
    const int t2 = B * 256 + t;
    if (t2 < SPAD * BATCH) {
        int s = t2 >> 5, b = t2 & 31;
        u32 off = LEVELS * 256u;       // pad s -> zero tile row 100
        if (s < SSIZE) {
            float v = x[b * SSIZE + s];
            float rr = rintf(v * (float)(LEVELS - 1));  // RTE = jnp.round
            int q = (int)rr;
            q = q < 0 ? 0 : (q > LEVELS - 1 ? LEVELS - 1 : q);
            off = (u32)q * 256u;       // LDS row byte offset (64 words * 4 B)
        }
        offb[s * BATCH + b] = off;
    }
    if (t2 < BATCH * NCLS) out[t2] = 0.0f;
}

// ---------------------------------------------------------------------------
// K2: bit-sliced bind+count. Block = 2048 dims (64 words, lane=word) x 32 b
// (4 waves x 8 b). Level-bit tile (101 rows x 256 B, row 100 = zeros) in LDS.
// Per s-pair per b: 2 conflict-free ds_read_b32 + XOR + full-adder + ripple
// into 5 carry planes (chunk 24 <= 62 -> no overflow). Epilogue nibble-spreads
// planes into u8 counts (32 B per (b,word)).
// ---------------------------------------------------------------------------
__global__ __launch_bounds__(256) void k_bind(const u32* __restrict__ idb,
                                              const u32* __restrict__ lvb,
                                              const u32* __restrict__ offb,
                                              u32* __restrict__ part,
                                              int chunk)
{
    __shared__ u32 tile[(LEVELS + 1) * 64];    // 25.9 KB
    const int W0 = blockIdx.x * 64;
    const int slot = blockIdx.y;
    const int tid = threadIdx.x;

    for (int t = tid; t < (LEVELS + 1) * 64; t += 256) {
        int r = t >> 6, w = t & 63;
        tile[t] = (r < LEVELS) ? lvb[(size_t)r * WPITCH + W0 + w] : 0;
    }
    __syncthreads();

    const int lane = tid & 63;
    const int B0 = __builtin_amdgcn_readfirstlane((tid >> 6) * 8);
    const int wq = W0 + lane;                  // < 320, always in range
    const int sBeg = slot * chunk;
    const int sEnd = min(SPAD, sBeg + chunk);  // even span

    u32 ones[8], c0[8], c1[8], c2[8], c3[8], c4[8];
#pragma unroll
    for (int b = 0; b < 8; ++b) { ones[b]=0; c0[b]=0; c1[b]=0; c2[b]=0; c3[b]=0; c4[b]=0; }

    for (int s = sBeg; s < sEnd; s += 2) {
        u32 u1 = idb[(size_t)s * WPITCH + wq];        // coalesced 256 B
        u32 u2 = idb[(size_t)(s + 1) * WPITCH + wq];
        const u32* o1 = offb + s * BATCH + B0;        // wave-uniform
        const u32* o2 = o1 + BATCH;
#pragma unroll
        for (int b = 0; b < 8; ++b) {
            u32 l1 = tile[(o1[b] >> 2) + lane];       // stride-1, conflict-free
            u32 l2 = tile[(o2[b] >> 2) + lane];
            u32 x1 = u1 ^ l1, x2 = u2 ^ l2;
            u32 t0 = x1 ^ x2;
            u32 sum = ones[b] ^ t0;
            u32 car = (x1 & x2) | (ones[b] & t0);
            ones[b] = sum;
            u32 t;
            t = c0[b] & car; c0[b] ^= car; car = t;
            t = c1[b] & car; c1[b] ^= car; car = t;
            t = c2[b] & car; c2[b] ^= car; car = t;
            t = c3[b] & car; c3[b] ^= car; car = t;
            c4[b] ^= car;                             // <= 62: no overflow
        }
    }

    // plane -> byte-count extraction: bit j of plane -> byte j bit of count.
#pragma unroll
    for (int b = 0; b < 8; ++b) {
        u32* dst = part + ((size_t)(slot * BATCH + B0 + b) * DPITCH + (size_t)wq * 32) / 4;
        u32 o[8];
#pragma unroll
        for (int g = 0; g < 8; ++g) {
            int sh = 4 * g;
            u32 n;
            n  =  (((ones[b] >> sh) & 0xFu) * 0x00204081u) & 0x01010101u;
            n |= ((((c0[b]  >> sh) & 0xFu) * 0x00204081u) & 0x01010101u) << 1;
            n |= ((((c1[b]  >> sh) & 0xFu) * 0x00204081u) & 0x01010101u) << 2;
            n |= ((((c2[b]  >> sh) & 0xFu) * 0x00204081u) & 0x01010101u) << 3;
            n |= ((((c3[b]  >> sh) & 0xFu) * 0x00204081u) & 0x01010101u) << 4;
            n |= ((((c4[b]  >> sh) & 0xFu) * 0x00204081u) & 0x01010101u) << 5;
            o[g] = n;
        }
        *(uint4*)(dst)     = make_uint4(o[0], o[1], o[2], o[3]);
        *(uint4*)(dst + 4) = make_uint4(o[4], o[5], o[6], o[7]);
    }
}

// ---------------------------------------------------------------------------
// K3 (fused enc+logit): block (q,b) owns dims [1024q, 1024q+1024) of batch b.
// Thread = 1 dword = 4 dim-counts; c-loop unrolled x8 (8 outstanding loads).
// u16-pair accumulate (max 26*24 = 624 < 65536). Threshold: enc=+1 <=>
// count <= 308 (multiset = 617-2*count is odd -> never 0). Then per-thread
// 4-dim dot with all 26 W rows (coalesced float4), wave shuffle-reduce,
// LDS cross-wave, atomicAdd into zeroed out.
// ---------------------------------------------------------------------------
__global__ __launch_bounds__(256) void k_encl(const u32* __restrict__ part,
                                              const float* __restrict__ W,
                                              float* __restrict__ out,
                                              int nch)
{
    const int b = blockIdx.y;
    const int q = blockIdx.x;
    const int t = threadIdx.x;
    const int dw = q * 256 + t;                 // dword index, < 2560
    const u32* p = part + (size_t)b * (DPITCH / 4) + dw;
    const size_t cs = (size_t)BATCH * (DPITCH / 4);

    u32 a01 = 0, a23 = 0;
    int c = 0;
    for (; c + 8 <= nch; c += 8) {
        u32 v[8];
#pragma unroll
        for (int k = 0; k < 8; ++k) v[k] = p[(size_t)(c + k) * cs];
#pragma unroll
        for (int k = 0; k < 8; ++k) {
            a01 += v[k] & 0x00FF00FFu;
            a23 += (v[k] >> 8) & 0x00FF00FFu;
        }
    }
    for (; c < nch; ++c) {
        u32 v = p[(size_t)c * cs];
        a01 += v & 0x00FF00FFu;
        a23 += (v >> 8) & 0x00FF00FFu;
    }
    const float e0 = (int)(a01 & 0xFFFFu) <= 308 ? 1.0f : -1.0f;
    const float e1 = (int)(a23 & 0xFFFFu) <= 308 ? 1.0f : -1.0f;
    const float e2 = (int)(a01 >> 16)     <= 308 ? 1.0f : -1.0f;
    const float e3 = (int)(a23 >> 16)     <= 308 ? 1.0f : -1.0f;

    float acc[NCLS];
    if (dw < DIMS / 4) {                        // dims 4dw..4dw+3 valid
#pragma unroll
        for (int cc = 0; cc < NCLS; ++cc) {
            float4 w4 = *(const float4*)(W + (size_t)cc * DIMS + 4 * dw);
            acc[cc] = fmaf(e0, w4.x, fmaf(e1, w4.y, fmaf(e2, w4.z, e3 * w4.w)));
        }
    } else {
#pragma unroll
        for (int cc = 0; cc < NCLS; ++cc) acc[cc] = 0.0f;
    }

#pragma unroll
    for (int cc = 0; cc < NCLS; ++cc) {
#pragma unroll
        for (int o = 32; o > 0; o >>= 1)
            acc[cc] += __shfl_xor(acc[cc], o);
    }

    __shared__ float red[4][NCLS];
    const int lane = t & 63, wv = t >> 6;
    if (lane == 0) {
#pragma unroll
        for (int cc = 0; cc < NCLS; ++cc) red[wv][cc] = acc[cc];
    }
    __syncthreads();
    if (t < NCLS) {
        float v = red[0][t] + red[1][t] + red[2][t] + red[3][t];
        atomicAdd(out + b * NCLS + t, v);
    }
}

// ---------------------------------------------------------------------------
extern "C" void kernel_launch(void* const* d_in, const int* in_sizes, int n_in,
                              void* d_out, int out_size, void* d_ws, size_t ws_size,
                              hipStream_t stream)
{
    const float* x   = (const float*)d_in[0];  // (32, 617)
    const float* idw = (const float*)d_in[1];  // (617, 10000)
    const float* lvw = (const float*)d_in[2];  // (100, 10000)
    const float* W   = (const float*)d_in[3];  // (26, 10000)
    float* out = (float*)d_out;                // (32, 26)

    char* ws = (char*)d_ws;
    u32* offb = (u32*)(ws + OFF_OFFB);
    u32* idb  = (u32*)(ws + OFF_IDB);
    u32* lvb  = (u32*)(ws + OFF_LVB);
    u32* part = (u32*)(ws + OFF_P8);

    // Default: 26 slots of 24 s each (8.3 MB). Fallback only if ws is tiny.
    size_t avail = ws_size > OFF_P8 ? ws_size - OFF_P8 : 0;
    int nch = NCH, chunk = CHUNK;
    if (avail < (size_t)NCH * SLOT_BYTES) {
        nch = (int)(avail / SLOT_BYTES);
        if (nch < 1) nch = 1;
        chunk = (SPAD + nch - 1) / nch;
        chunk = (chunk + 1) & ~1;
        if (chunk > 62) chunk = 62;            // CSA capacity bound
        nch = (SPAD + chunk - 1) / chunk;
    }

    dim3 g1(10, PK_ROWS);                      // 7240 blocks
    k_pack<<<g1, 256, 0, stream>>>(x, idw, lvw, idb, lvb, offb, out);

    dim3 g2(NTILE, nch);                       // (5, 26) = 130 blocks
    k_bind<<<g2, 256, 0, stream>>>(idb, lvb, offb, part, chunk);

    dim3 g3(10, BATCH);                        // 320 blocks
    k_encl<<<g3, 256, 0, stream>>>(part, W, out, nch);
}

// Round 6
// 100.125 us; speedup vs baseline: 1.5529x; 1.0675x over previous
//
#include <hip/hip_runtime.h>

typedef unsigned int u32;
typedef unsigned char u8;
typedef unsigned long long u64;

// Problem constants
#define DIMS   10000
#define LEVELS 100
#define SSIZE  617
#define SPAD   624        // padded s (rows 617..623 zero in idb)
#define NCLS   26
#define BATCH  32
#define WORDS  313        // ceil(10000/32) real sign-bit words per row
#define WPITCH 320        // padded word pitch; words 313..319 = 0
#define DPITCH 10240      // byte-count pitch per (slot,b) = WPITCH*32
#define NTILE  5          // d-tiles of 64 words (2048 dims)
#define NCH    26         // s-chunks of 24 (624 = 26*24), counts <= 24 < 63
#define CHUNK  24

// ws layout (bytes)
#define OFF_OFFB 0x000000u  // 624*32*4   =  79,872
#define OFF_IDB  0x020000u  // 624*320*4  = 798,720
#define OFF_LVB  0x100000u  // 100*320*4  = 128,000
#define OFF_P8   0x140000u  // nch*32*10240 (26 slots = 8.3 MB)
#define SLOT_BYTES ((size_t)BATCH * DPITCH)   // 327,680

#define PK_ROWS (SPAD + LEVELS)   // 724: 0..616 id, 617..623 id-pad, 624..723 lvl

// ---------------------------------------------------------------------------
// K1: sign-pack, fully coalesced. Grid (10, 724): block (g, r) covers dims
// [1024g, 1024g+1024) of row r. Thread t loads ONE float4 (16 B/lane,
// perfect coalescing), makes a 4-bit sign nibble, LDS transpose, 32 threads
// emit words. Rows 617..623 and pad words 313..319 get zeros. Low flat-id
// blocks also quantize x -> LDS-row byte offsets (transposed [s][b]) and
// zero d_out.
// ---------------------------------------------------------------------------
__global__ __launch_bounds__(256) void k_pack(const float* __restrict__ x,
                                              const float* __restrict__ idw,
                                              const float* __restrict__ lvw,
                                              u32* __restrict__ idb,
                                              u32* __restrict__ lvb,
                                              u32* __restrict__ offb,
                                              float* __restrict__ out)
{
    const int g = blockIdx.x;          // 0..9
    const int r = blockIdx.y;          // 0..723
    const int t = threadIdx.x;
    const bool isLvl = r >= SPAD;
    const int d0 = g * 1024 + 4 * t;

    u32 nib = 0;
    if (d0 + 3 < DIMS && (isLvl || r < SSIZE)) {
        const float* src = isLvl ? (lvw + (size_t)(r - SPAD) * DIMS)
                                 : (idw + (size_t)r * DIMS);
        float4 f = *(const float4*)(src + d0);
        nib =  (__builtin_bit_cast(u32, f.x) >> 31)
            | ((__builtin_bit_cast(u32, f.y) >> 31) << 1)
            | ((__builtin_bit_cast(u32, f.z) >> 31) << 2)
            | ((__builtin_bit_cast(u32, f.w) >> 31) << 3);
    }
    __shared__ u32 nibs[256];
    nibs[t] = nib;
    __syncthreads();
    if (t < 32) {
        u32 w = 0;
#pragma unroll
        for (int j = 0; j < 8; ++j) w |= nibs[t * 8 + j] << (4 * j);
        u32* dst = isLvl ? (lvb + (size_t)(r - SPAD) * WPITCH)
                         : (idb + (size_t)r * WPITCH);
        dst[g * 32 + t] = w;           // g*32+t spans 0..319 = WPITCH
    }

    // Side work on the first 78+ blocks (flat id B = r*10+g).
    const int B = r * 10 + g;
    const int t2 = B * 256 + t;
    if (t2 < SPAD * BATCH) {
        int s = t2 >> 5, b = t2 & 31;
        u32 off = LEVELS * 256u;       // pad s -> zero tile row 100
        if (s < SSIZE) {
            float v = x[b * SSIZE + s];
            float rr = rintf(v * (float)(LEVELS - 1));  // RTE = jnp.round
            int q = (int)rr;
            q = q < 0 ? 0 : (q > LEVELS - 1 ? LEVELS - 1 : q);
            off = (u32)q * 256u;       // LDS row byte offset (64 words * 4 B)
        }
        offb[s * BATCH + b] = off;
    }
    if (t2 < BATCH * NCLS) out[t2] = 0.0f;
}

// ---------------------------------------------------------------------------
// Shared epilogue: CSA planes -> u8 counts, 32 B per (b, word).
// ---------------------------------------------------------------------------
__device__ __forceinline__ void spread_store(u32* __restrict__ part,
                                             int slot, int B0, int wq,
                                             const u32 ones[8], const u32 c0[8],
                                             const u32 c1[8], const u32 c2[8],
                                             const u32 c3[8], const u32 c4[8])
{
#pragma unroll
    for (int b = 0; b < 8; ++b) {
        u32* dst = part + ((size_t)(slot * BATCH + B0 + b) * DPITCH + (size_t)wq * 32) / 4;
        u32 o[8];
#pragma unroll
        for (int g = 0; g < 8; ++g) {
            int sh = 4 * g;
            u32 n;
            n  =  (((ones[b] >> sh) & 0xFu) * 0x00204081u) & 0x01010101u;
            n |= ((((c0[b]  >> sh) & 0xFu) * 0x00204081u) & 0x01010101u) << 1;
            n |= ((((c1[b]  >> sh) & 0xFu) * 0x00204081u) & 0x01010101u) << 2;
            n |= ((((c2[b]  >> sh) & 0xFu) * 0x00204081u) & 0x01010101u) << 3;
            n |= ((((c3[b]  >> sh) & 0xFu) * 0x00204081u) & 0x01010101u) << 4;
            n |= ((((c4[b]  >> sh) & 0xFu) * 0x00204081u) & 0x01010101u) << 5;
            o[g] = n;
        }
        *(uint4*)(dst)     = make_uint4(o[0], o[1], o[2], o[3]);
        *(uint4*)(dst + 4) = make_uint4(o[4], o[5], o[6], o[7]);
    }
}

#define CSA_STEP(b, x1, x2)                                                   \
    {                                                                         \
        u32 t0 = (x1) ^ (x2);                                                 \
        u32 sum = ones[b] ^ t0;                                               \
        u32 car = ((x1) & (x2)) | (ones[b] & t0);                             \
        ones[b] = sum;                                                        \
        u32 tt;                                                               \
        tt = c0[b] & car; c0[b] ^= car; car = tt;                             \
        tt = c1[b] & car; c1[b] ^= car; car = tt;                             \
        tt = c2[b] & car; c2[b] ^= car; car = tt;                             \
        tt = c3[b] & car; c3[b] ^= car; car = tt;                             \
        c4[b] ^= car;                                                         \
    }

// ---------------------------------------------------------------------------
// K2 (compile-time chunk): bit-sliced bind+count. Block = 2048 dims (64 words,
// lane=word) x 32 b (4 waves x 8 b). Staging: 25 pre-issued unconditional
// loads (rows 0..99; row 100 = zero) -> one latency round. Main s-loop fully
// unrolled: all CH idb loads outstanding, then pure VALU CSA.
// ---------------------------------------------------------------------------
template <int CH>
__global__ __launch_bounds__(256) void k_bind_t(const u32* __restrict__ idb,
                                                const u32* __restrict__ lvb,
                                                const u32* __restrict__ offb,
                                                u32* __restrict__ part)
{
    __shared__ u32 tile[(LEVELS + 1) * 64];    // 6464 dwords = 25.9 KB
    const int W0 = blockIdx.x * 64;
    const int slot = blockIdx.y;
    const int tid = threadIdx.x;

    {   // rows 0..99 = 6400 dwords = 25 x 256; all loads issued up-front
        u32 stg[25];
#pragma unroll
        for (int k = 0; k < 25; ++k) {
            int idx = k * 256 + tid;           // row = idx>>6 < 100 always
            stg[k] = lvb[(size_t)(idx >> 6) * WPITCH + W0 + (idx & 63)];
        }
#pragma unroll
        for (int k = 0; k < 25; ++k) tile[k * 256 + tid] = stg[k];
        if (tid < 64) tile[6400 + tid] = 0;    // zero row 100 (s-pad)
    }
    __syncthreads();

    const int lane = tid & 63;
    const int B0 = __builtin_amdgcn_readfirstlane((tid >> 6) * 8);
    const int wq = W0 + lane;                  // < 320, always in range
    const int sBeg = slot * CH;

    u32 ones[8], c0[8], c1[8], c2[8], c3[8], c4[8];
#pragma unroll
    for (int b = 0; b < 8; ++b) { ones[b]=0; c0[b]=0; c1[b]=0; c2[b]=0; c3[b]=0; c4[b]=0; }

#pragma unroll
    for (int i = 0; i < CH / 2; ++i) {
        const int s = sBeg + 2 * i;
        u32 u1 = idb[(size_t)s * WPITCH + wq];        // coalesced 256 B
        u32 u2 = idb[(size_t)(s + 1) * WPITCH + wq];
        const u32* o1 = offb + s * BATCH + B0;        // wave-uniform s_load
        const u32* o2 = o1 + BATCH;
#pragma unroll
        for (int b = 0; b < 8; ++b) {
            u32 l1 = tile[(o1[b] >> 2) + lane];       // stride-1, conflict-free
            u32 l2 = tile[(o2[b] >> 2) + lane];
            u32 x1 = u1 ^ l1, x2 = u2 ^ l2;
            CSA_STEP(b, x1, x2);                      // counts <= CH <= 62
        }
    }
    spread_store(part, slot, B0, wq, ones, c0, c1, c2, c3, c4);
}

// Generic fallback (runtime chunk) — only used if ws is unexpectedly small.
__global__ __launch_bounds__(256) void k_bind_g(const u32* __restrict__ idb,
                                                const u32* __restrict__ lvb,
                                                const u32* __restrict__ offb,
                                                u32* __restrict__ part,
                                                int chunk)
{
    __shared__ u32 tile[(LEVELS + 1) * 64];
    const int W0 = blockIdx.x * 64;
    const int slot = blockIdx.y;
    const int tid = threadIdx.x;
    for (int t = tid; t < (LEVELS + 1) * 64; t += 256) {
        int r = t >> 6, w = t & 63;
        tile[t] = (r < LEVELS) ? lvb[(size_t)r * WPITCH + W0 + w] : 0;
    }
    __syncthreads();
    const int lane = tid & 63;
    const int B0 = __builtin_amdgcn_readfirstlane((tid >> 6) * 8);
    const int wq = W0 + lane;
    const int sBeg = slot * chunk;
    const int sEnd = min(SPAD, sBeg + chunk);
    u32 ones[8], c0[8], c1[8], c2[8], c3[8], c4[8];
#pragma unroll
    for (int b = 0; b < 8; ++b) { ones[b]=0; c0[b]=0; c1[b]=0; c2[b]=0; c3[b]=0; c4[b]=0; }
    for (int s = sBeg; s < sEnd; s += 2) {
        u32 u1 = idb[(size_t)s * WPITCH + wq];
        u32 u2 = idb[(size_t)(s + 1) * WPITCH + wq];
        const u32* o1 = offb + s * BATCH + B0;
        const u32* o2 = o1 + BATCH;
#pragma unroll
        for (int b = 0; b < 8; ++b) {
            u32 l1 = tile[(o1[b] >> 2) + lane];
            u32 l2 = tile[(o2[b] >> 2) + lane];
            u32 x1 = u1 ^ l1, x2 = u2 ^ l2;
            CSA_STEP(b, x1, x2);
        }
    }
    spread_store(part, slot, B0, wq, ones, c0, c1, c2, c3, c4);
}

// ---------------------------------------------------------------------------
// K3 (fused enc+logit, compile-time nch): block (q,b) owns dims
// [1024q, 1024q+1024) of batch b. Thread = 1 dword = 4 dim-counts; all NCHT
// slot loads issued up-front (one latency round). u16-pair accumulate
// (max 26*24 = 624 < 65536). enc=+1 <=> count <= 308 (multiset = 617-2*count
// is odd -> never 0). Per-thread 4-dim dot with 26 W rows (coalesced float4),
// wave shuffle-reduce, LDS cross-wave, atomicAdd into zeroed out.
// ---------------------------------------------------------------------------
template <int NCHT>
__global__ __launch_bounds__(256) void k_encl_t(const u32* __restrict__ part,
                                                const float* __restrict__ W,
                                                float* __restrict__ out)
{
    const int b = blockIdx.y;
    const int q = blockIdx.x;
    const int t = threadIdx.x;
    const int dw = q * 256 + t;                 // dword index, < 2560
    const u32* p = part + (size_t)b * (DPITCH / 4) + dw;
    const size_t cs = (size_t)BATCH * (DPITCH / 4);

    u32 v[NCHT];
#pragma unroll
    for (int c = 0; c < NCHT; ++c) v[c] = p[(size_t)c * cs];  // all outstanding
    u32 a01 = 0, a23 = 0;
#pragma unroll
    for (int c = 0; c < NCHT; ++c) {
        a01 += v[c] & 0x00FF00FFu;
        a23 += (v[c] >> 8) & 0x00FF00FFu;
    }
    const float e0 = (int)(a01 & 0xFFFFu) <= 308 ? 1.0f : -1.0f;
    const float e1 = (int)(a23 & 0xFFFFu) <= 308 ? 1.0f : -1.0f;
    const float e2 = (int)(a01 >> 16)     <= 308 ? 1.0f : -1.0f;
    const float e3 = (int)(a23 >> 16)     <= 308 ? 1.0f : -1.0f;

    float acc[NCLS];
    if (dw < DIMS / 4) {
#pragma unroll
        for (int cc = 0; cc < NCLS; ++cc) {
            float4 w4 = *(const float4*)(W + (size_t)cc * DIMS + 4 * dw);
            acc[cc] = fmaf(e0, w4.x, fmaf(e1, w4.y, fmaf(e2, w4.z, e3 * w4.w)));
        }
    } else {
#pragma unroll
        for (int cc = 0; cc < NCLS; ++cc) acc[cc] = 0.0f;
    }

#pragma unroll
    for (int cc = 0; cc < NCLS; ++cc) {
#pragma unroll
        for (int o = 32; o > 0; o >>= 1)
            acc[cc] += __shfl_xor(acc[cc], o);
    }
    __shared__ float red[4][NCLS];
    const int lane = t & 63, wv = t >> 6;
    if (lane == 0) {
#pragma unroll
        for (int cc = 0; cc < NCLS; ++cc) red[wv][cc] = acc[cc];
    }
    __syncthreads();
    if (t < NCLS) {
        float vv = red[0][t] + red[1][t] + red[2][t] + red[3][t];
        atomicAdd(out + b * NCLS + t, vv);
    }
}

// Generic fallback (runtime nch).
__global__ __launch_bounds__(256) void k_encl_g(const u32* __restrict__ part,
                                                const float* __restrict__ W,
                                                float* __restrict__ out,
                                                int nch)
{
    const int b = blockIdx.y;
    const int q = blockIdx.x;
    const int t = threadIdx.x;
    const int dw = q * 256 + t;
    const u32* p = part + (size_t)b * (DPITCH / 4) + dw;
    const size_t cs = (size_t)BATCH * (DPITCH / 4);
    u32 a01 = 0, a23 = 0;
    for (int c = 0; c < nch; ++c) {
        u32 v = p[(size_t)c * cs];
        a01 += v & 0x00FF00FFu;
        a23 += (v >> 8) & 0x00FF00FFu;
    }
    const float e0 = (int)(a01 & 0xFFFFu) <= 308 ? 1.0f : -1.0f;
    const float e1 = (int)(a23 & 0xFFFFu) <= 308 ? 1.0f : -1.0f;
    const float e2 = (int)(a01 >> 16)     <= 308 ? 1.0f : -1.0f;
    const float e3 = (int)(a23 >> 16)     <= 308 ? 1.0f : -1.0f;
    float acc[NCLS];
    if (dw < DIMS / 4) {
#pragma unroll
        for (int cc = 0; cc < NCLS; ++cc) {
            float4 w4 = *(const float4*)(W + (size_t)cc * DIMS + 4 * dw);
            acc[cc] = fmaf(e0, w4.x, fmaf(e1, w4.y, fmaf(e2, w4.z, e3 * w4.w)));
        }
    } else {
#pragma unroll
        for (int cc = 0; cc < NCLS; ++cc) acc[cc] = 0.0f;
    }
#pragma unroll
    for (int cc = 0; cc < NCLS; ++cc) {
#pragma unroll
        for (int o = 32; o > 0; o >>= 1)
            acc[cc] += __shfl_xor(acc[cc], o);
    }
    __shared__ float red[4][NCLS];
    const int lane = t & 63, wv = t >> 6;
    if (lane == 0) {
#pragma unroll
        for (int cc = 0; cc < NCLS; ++cc) red[wv][cc] = acc[cc];
    }
    __syncthreads();
    if (t < NCLS) {
        float vv = red[0][t] + red[1][t] + red[2][t] + red[3][t];
        atomicAdd(out + b * NCLS + t, vv);
    }
}

// ---------------------------------------------------------------------------
extern "C" void kernel_launch(void* const* d_in, const int* in_sizes, int n_in,
                              void* d_out, int out_size, void* d_ws, size_t ws_size,
                              hipStream_t stream)
{
    const float* x   = (const float*)d_in[0];  // (32, 617)
    const float* idw = (const float*)d_in[1];  // (617, 10000)
    const float* lvw = (const float*)d_in[2];  // (100, 10000)
    const float* W   = (const float*)d_in[3];  // (26, 10000)
    float* out = (float*)d_out;                // (32, 26)

    char* ws = (char*)d_ws;
    u32* offb = (u32*)(ws + OFF_OFFB);
    u32* idb  = (u32*)(ws + OFF_IDB);
    u32* lvb  = (u32*)(ws + OFF_LVB);
    u32* part = (u32*)(ws + OFF_P8);

    size_t avail = ws_size > OFF_P8 ? ws_size - OFF_P8 : 0;
    const bool fast = avail >= (size_t)NCH * SLOT_BYTES;   // always true @256MiB

    dim3 g1(10, PK_ROWS);                      // 7240 blocks
    k_pack<<<g1, 256, 0, stream>>>(x, idw, lvw, idb, lvb, offb, out);

    if (fast) {
        dim3 g2(NTILE, NCH);                   // (5, 26) = 130 blocks
        k_bind_t<CHUNK><<<g2, 256, 0, stream>>>(idb, lvb, offb, part);
        dim3 g3(10, BATCH);                    // 320 blocks
        k_encl_t<NCH><<<g3, 256, 0, stream>>>(part, W, out);
    } else {
        int nch = (int)(avail / SLOT_BYTES);
        if (nch < 1) nch = 1;
        int chunk = (SPAD + nch - 1) / nch;
        chunk = (chunk + 1) & ~1;
        if (chunk > 62) chunk = 62;            // CSA capacity bound
        nch = (SPAD + chunk - 1) / chunk;
        dim3 g2(NTILE, nch);
        k_bind_g<<<g2, 256, 0, stream>>>(idb, lvb, offb, part, chunk);
        dim3 g3(10, BATCH);
        k_encl_g<<<g3, 256, 0, stream>>>(part, W, out, nch);
    }
}

// Round 7
// 95.242 us; speedup vs baseline: 1.6325x; 1.0513x over previous
//
#include <hip/hip_runtime.h>

typedef unsigned int u32;
typedef unsigned char u8;
typedef unsigned long long u64;

// Problem constants
#define DIMS   10000
#define LEVELS 100
#define SSIZE  617
#define SPAD   624        // padded s (rows 617..623 zero in idb, offw -> zero row)
#define NCLS   26
#define BATCH  32
#define WORDS  313        // ceil(10000/32) real sign-bit words per row
#define WPITCH 320        // padded word pitch; words 313..319 = 0
#define DPITCH 10240      // byte-count pitch per (slot,b) = WPITCH*32
#define NTILE  5          // d-tiles of 64 words (2048 dims)
#define NCH    26         // s-chunks of 24 (624 = 26*24); counts <= 24 <= 31 cap
#define CHUNK  24

// ws layout (bytes)
#define OFF_OFFW 0x000000u  // 624*32*4    =  79,872  (word offsets idx*WPITCH)
#define OFF_IDB  0x020000u  // 624*320*4   = 798,720
#define OFF_LVB  0x100000u  // 101*320*4   = 129,280  (row 100 = zeros, s-pad)
#define OFF_P8   0x140000u  // nch*32*10240 (26 slots = 8.3 MB)
#define SLOT_BYTES ((size_t)BATCH * DPITCH)   // 327,680

#define PK_ROWS (SPAD + LEVELS + 1)  // 725: id rows 0..623, lvl rows 0..100

// ---------------------------------------------------------------------------
// K1: sign-pack, fully coalesced. Grid (10, 725): block (g, r) covers dims
// [1024g, 1024g+1024) of row r. Thread t loads ONE float4 (16 B/lane), makes
// a sign nibble, LDS transpose, 32 threads emit words. id rows 617..623,
// lvl row 100, and pad words 313..319 all get zeros. Low flat-id blocks also
// quantize x -> lvb WORD offsets (transposed [s][b]) and zero d_out.
// ---------------------------------------------------------------------------
__global__ __launch_bounds__(256) void k_pack(const float* __restrict__ x,
                                              const float* __restrict__ idw,
                                              const float* __restrict__ lvw,
                                              u32* __restrict__ idb,
                                              u32* __restrict__ lvb,
                                              u32* __restrict__ offw,
                                              float* __restrict__ out)
{
    const int g = blockIdx.x;          // 0..9
    const int r = blockIdx.y;          // 0..724
    const int t = threadIdx.x;
    const bool isLvl = r >= SPAD;
    const int rl = r - SPAD;           // lvl row if isLvl
    const int d0 = g * 1024 + 4 * t;

    u32 nib = 0;
    const bool rowValid = isLvl ? (rl < LEVELS) : (r < SSIZE);
    if (d0 + 3 < DIMS && rowValid) {
        const float* src = isLvl ? (lvw + (size_t)rl * DIMS)
                                 : (idw + (size_t)r * DIMS);
        float4 f = *(const float4*)(src + d0);
        nib =  (__builtin_bit_cast(u32, f.x) >> 31)
            | ((__builtin_bit_cast(u32, f.y) >> 31) << 1)
            | ((__builtin_bit_cast(u32, f.z) >> 31) << 2)
            | ((__builtin_bit_cast(u32, f.w) >> 31) << 3);
    }
    __shared__ u32 nibs[256];
    nibs[t] = nib;
    __syncthreads();
    if (t < 32) {
        u32 w = 0;
#pragma unroll
        for (int j = 0; j < 8; ++j) w |= nibs[t * 8 + j] << (4 * j);
        u32* dst = isLvl ? (lvb + (size_t)rl * WPITCH)
                         : (idb + (size_t)r * WPITCH);
        dst[g * 32 + t] = w;           // g*32+t spans 0..319 = WPITCH
    }

    // Side work on the first 78+ blocks (flat id B = r*10+g).
    const int B = r * 10 + g;
    const int t2 = B * 256 + t;
    if (t2 < SPAD * BATCH) {
        int s = t2 >> 5, b = t2 & 31;
        u32 off = (u32)LEVELS * WPITCH;        // pad s -> zero lvb row 100
        if (s < SSIZE) {
            float v = x[b * SSIZE + s];
            float rr = rintf(v * (float)(LEVELS - 1));  // RTE = jnp.round
            int q = (int)rr;
            q = q < 0 ? 0 : (q > LEVELS - 1 ? LEVELS - 1 : q);
            off = (u32)q * WPITCH;             // lvb word offset of level row
        }
        offw[s * BATCH + b] = off;
    }
    if (t2 < BATCH * NCLS) out[t2] = 0.0f;
}

// ---------------------------------------------------------------------------
// K2: bit-sliced bind+count, NO LDS — level rows gathered straight from L2
// (lvb = 129 KB, resident in every XCD's L2). Block = ONE wave: 64 words
// (lane=word) x 4 batches (B0 = 4*blockIdx.y -> offsets scalar by
// construction) x CH s of one slot. All inner loads are VMEM (in-order,
// deep outstanding queue) — no ds_read/lgkmcnt entanglement, no barrier.
// CSA planes ones..c3 (capacity 31 >= CH=24). Epilogue nibble-spreads
// planes into u8 counts (32 B per (b,word)).
// ---------------------------------------------------------------------------
template <int CH>
__global__ __launch_bounds__(64) void k_bind_t(const u32* __restrict__ idb,
                                               const u32* __restrict__ lvb,
                                               const u32* __restrict__ offw,
                                               u32* __restrict__ part)
{
    const int wq   = blockIdx.x * 64 + threadIdx.x;   // word, < 320
    const int B0   = blockIdx.y * 4;                  // batch group (SGPR)
    const int slot = blockIdx.z;
    const int sBeg = slot * CH;

    u32 ones[4], c0[4], c1[4], c2[4], c3[4];
#pragma unroll
    for (int b = 0; b < 4; ++b) { ones[b]=0; c0[b]=0; c1[b]=0; c2[b]=0; c3[b]=0; }

#pragma unroll
    for (int i = 0; i < CH / 2; ++i) {
        const int s = sBeg + 2 * i;
        u32 u1 = idb[(size_t)s * WPITCH + wq];        // coalesced 256 B
        u32 u2 = idb[(size_t)(s + 1) * WPITCH + wq];
        const u32* o1 = offw + s * BATCH + B0;        // scalar address
        const u32* o2 = o1 + BATCH;
#pragma unroll
        for (int b = 0; b < 4; ++b) {
            u32 l1 = lvb[o1[b] + wq];                 // L2-hit gather, 256 B
            u32 l2 = lvb[o2[b] + wq];
            u32 x1 = u1 ^ l1, x2 = u2 ^ l2;
            u32 t0 = x1 ^ x2;
            u32 sum = ones[b] ^ t0;
            u32 car = (x1 & x2) | (ones[b] & t0);
            ones[b] = sum;
            u32 tt;
            tt = c0[b] & car; c0[b] ^= car; car = tt;
            tt = c1[b] & car; c1[b] ^= car; car = tt;
            tt = c2[b] & car; c2[b] ^= car; car = tt;
            c3[b] ^= car;                             // counts <= 24 <= 31
        }
    }

    // plane -> byte-count extraction: bit j of plane -> byte j bit of count.
#pragma unroll
    for (int b = 0; b < 4; ++b) {
        u32* dst = part + ((size_t)(slot * BATCH + B0 + b) * DPITCH + (size_t)wq * 32) / 4;
        u32 o[8];
#pragma unroll
        for (int g = 0; g < 8; ++g) {
            int sh = 4 * g;
            u32 n;
            n  =  (((ones[b] >> sh) & 0xFu) * 0x00204081u) & 0x01010101u;
            n |= ((((c0[b]  >> sh) & 0xFu) * 0x00204081u) & 0x01010101u) << 1;
            n |= ((((c1[b]  >> sh) & 0xFu) * 0x00204081u) & 0x01010101u) << 2;
            n |= ((((c2[b]  >> sh) & 0xFu) * 0x00204081u) & 0x01010101u) << 3;
            n |= ((((c3[b]  >> sh) & 0xFu) * 0x00204081u) & 0x01010101u) << 4;
            o[g] = n;
        }
        *(uint4*)(dst)     = make_uint4(o[0], o[1], o[2], o[3]);
        *(uint4*)(dst + 4) = make_uint4(o[4], o[5], o[6], o[7]);
    }
}

// Generic fallback (runtime chunk <= 62, 6 planes) — only for tiny ws.
__global__ __launch_bounds__(64) void k_bind_g(const u32* __restrict__ idb,
                                               const u32* __restrict__ lvb,
                                               const u32* __restrict__ offw,
                                               u32* __restrict__ part,
                                               int chunk)
{
    const int wq   = blockIdx.x * 64 + threadIdx.x;
    const int B0   = blockIdx.y * 4;
    const int slot = blockIdx.z;
    const int sBeg = slot * chunk;
    const int sEnd = min(SPAD, sBeg + chunk);

    u32 ones[4], c0[4], c1[4], c2[4], c3[4], c4[4];
#pragma unroll
    for (int b = 0; b < 4; ++b) { ones[b]=0; c0[b]=0; c1[b]=0; c2[b]=0; c3[b]=0; c4[b]=0; }

    for (int s = sBeg; s < sEnd; s += 2) {
        u32 u1 = idb[(size_t)s * WPITCH + wq];
        u32 u2 = idb[(size_t)(s + 1) * WPITCH + wq];
        const u32* o1 = offw + s * BATCH + B0;
        const u32* o2 = o1 + BATCH;
#pragma unroll
        for (int b = 0; b < 4; ++b) {
            u32 l1 = lvb[o1[b] + wq];
            u32 l2 = lvb[o2[b] + wq];
            u32 x1 = u1 ^ l1, x2 = u2 ^ l2;
            u32 t0 = x1 ^ x2;
            u32 sum = ones[b] ^ t0;
            u32 car = (x1 & x2) | (ones[b] & t0);
            ones[b] = sum;
            u32 tt;
            tt = c0[b] & car; c0[b] ^= car; car = tt;
            tt = c1[b] & car; c1[b] ^= car; car = tt;
            tt = c2[b] & car; c2[b] ^= car; car = tt;
            tt = c3[b] & car; c3[b] ^= car; car = tt;
            c4[b] ^= car;                             // capacity 63
        }
    }
#pragma unroll
    for (int b = 0; b < 4; ++b) {
        u32* dst = part + ((size_t)(slot * BATCH + B0 + b) * DPITCH + (size_t)wq * 32) / 4;
        u32 o[8];
#pragma unroll
        for (int g = 0; g < 8; ++g) {
            int sh = 4 * g;
            u32 n;
            n  =  (((ones[b] >> sh) & 0xFu) * 0x00204081u) & 0x01010101u;
            n |= ((((c0[b]  >> sh) & 0xFu) * 0x00204081u) & 0x01010101u) << 1;
            n |= ((((c1[b]  >> sh) & 0xFu) * 0x00204081u) & 0x01010101u) << 2;
            n |= ((((c2[b]  >> sh) & 0xFu) * 0x00204081u) & 0x01010101u) << 3;
            n |= ((((c3[b]  >> sh) & 0xFu) * 0x00204081u) & 0x01010101u) << 4;
            n |= ((((c4[b]  >> sh) & 0xFu) * 0x00204081u) & 0x01010101u) << 5;
            o[g] = n;
        }
        *(uint4*)(dst)     = make_uint4(o[0], o[1], o[2], o[3]);
        *(uint4*)(dst + 4) = make_uint4(o[4], o[5], o[6], o[7]);
    }
}

// ---------------------------------------------------------------------------
// K3 (fused enc+logit, compile-time nch): block (q,b) owns dims
// [1024q, 1024q+1024) of batch b. Thread = 1 dword = 4 dim-counts; all NCHT
// slot loads issued up-front. u16-pair accumulate (max 26*24 = 624 < 65536).
// enc=+1 <=> count <= 308 (multiset = 617-2*count is odd -> never 0).
// Per-thread 4-dim dot with 26 W rows (coalesced float4), wave
// shuffle-reduce, LDS cross-wave, atomicAdd into zeroed out.
// ---------------------------------------------------------------------------
template <int NCHT>
__global__ __launch_bounds__(256) void k_encl_t(const u32* __restrict__ part,
                                                const float* __restrict__ W,
                                                float* __restrict__ out)
{
    const int b = blockIdx.y;
    const int q = blockIdx.x;
    const int t = threadIdx.x;
    const int dw = q * 256 + t;                 // dword index, < 2560
    const u32* p = part + (size_t)b * (DPITCH / 4) + dw;
    const size_t cs = (size_t)BATCH * (DPITCH / 4);

    u32 v[NCHT];
#pragma unroll
    for (int c = 0; c < NCHT; ++c) v[c] = p[(size_t)c * cs];  // all outstanding
    u32 a01 = 0, a23 = 0;
#pragma unroll
    for (int c = 0; c < NCHT; ++c) {
        a01 += v[c] & 0x00FF00FFu;
        a23 += (v[c] >> 8) & 0x00FF00FFu;
    }
    const float e0 = (int)(a01 & 0xFFFFu) <= 308 ? 1.0f : -1.0f;
    const float e1 = (int)(a23 & 0xFFFFu) <= 308 ? 1.0f : -1.0f;
    const float e2 = (int)(a01 >> 16)     <= 308 ? 1.0f : -1.0f;
    const float e3 = (int)(a23 >> 16)     <= 308 ? 1.0f : -1.0f;

    float acc[NCLS];
    if (dw < DIMS / 4) {
#pragma unroll
        for (int cc = 0; cc < NCLS; ++cc) {
            float4 w4 = *(const float4*)(W + (size_t)cc * DIMS + 4 * dw);
            acc[cc] = fmaf(e0, w4.x, fmaf(e1, w4.y, fmaf(e2, w4.z, e3 * w4.w)));
        }
    } else {
#pragma unroll
        for (int cc = 0; cc < NCLS; ++cc) acc[cc] = 0.0f;
    }

#pragma unroll
    for (int cc = 0; cc < NCLS; ++cc) {
#pragma unroll
        for (int o = 32; o > 0; o >>= 1)
            acc[cc] += __shfl_xor(acc[cc], o);
    }
    __shared__ float red[4][NCLS];
    const int lane = t & 63, wv = t >> 6;
    if (lane == 0) {
#pragma unroll
        for (int cc = 0; cc < NCLS; ++cc) red[wv][cc] = acc[cc];
    }
    __syncthreads();
    if (t < NCLS) {
        float vv = red[0][t] + red[1][t] + red[2][t] + red[3][t];
        atomicAdd(out + b * NCLS + t, vv);
    }
}

// Generic fallback (runtime nch).
__global__ __launch_bounds__(256) void k_encl_g(const u32* __restrict__ part,
                                                const float* __restrict__ W,
                                                float* __restrict__ out,
                                                int nch)
{
    const int b = blockIdx.y;
    const int q = blockIdx.x;
    const int t = threadIdx.x;
    const int dw = q * 256 + t;
    const u32* p = part + (size_t)b * (DPITCH / 4) + dw;
    const size_t cs = (size_t)BATCH * (DPITCH / 4);
    u32 a01 = 0, a23 = 0;
    for (int c = 0; c < nch; ++c) {
        u32 v = p[(size_t)c * cs];
        a01 += v & 0x00FF00FFu;
        a23 += (v >> 8) & 0x00FF00FFu;
    }
    const float e0 = (int)(a01 & 0xFFFFu) <= 308 ? 1.0f : -1.0f;
    const float e1 = (int)(a23 & 0xFFFFu) <= 308 ? 1.0f : -1.0f;
    const float e2 = (int)(a01 >> 16)     <= 308 ? 1.0f : -1.0f;
    const float e3 = (int)(a23 >> 16)     <= 308 ? 1.0f : -1.0f;
    float acc[NCLS];
    if (dw < DIMS / 4) {
#pragma unroll
        for (int cc = 0; cc < NCLS; ++cc) {
            float4 w4 = *(const float4*)(W + (size_t)cc * DIMS + 4 * dw);
            acc[cc] = fmaf(e0, w4.x, fmaf(e1, w4.y, fmaf(e2, w4.z, e3 * w4.w)));
        }
    } else {
#pragma unroll
        for (int cc = 0; cc < NCLS; ++cc) acc[cc] = 0.0f;
    }
#pragma unroll
    for (int cc = 0; cc < NCLS; ++cc) {
#pragma unroll
        for (int o = 32; o > 0; o >>= 1)
            acc[cc] += __shfl_xor(acc[cc], o);
    }
    __shared__ float red[4][NCLS];
    const int lane = t & 63, wv = t >> 6;
    if (lane == 0) {
#pragma unroll
        for (int cc = 0; cc < NCLS; ++cc) red[wv][cc] = acc[cc];
    }
    __syncthreads();
    if (t < NCLS) {
        float vv = red[0][t] + red[1][t] + red[2][t] + red[3][t];
        atomicAdd(out + b * NCLS + t, vv);
    }
}

// ---------------------------------------------------------------------------
extern "C" void kernel_launch(void* const* d_in, const int* in_sizes, int n_in,
                              void* d_out, int out_size, void* d_ws, size_t ws_size,
                              hipStream_t stream)
{
    const float* x   = (const float*)d_in[0];  // (32, 617)
    const float* idw = (const float*)d_in[1];  // (617, 10000)
    const float* lvw = (const float*)d_in[2];  // (100, 10000)
    const float* W   = (const float*)d_in[3];  // (26, 10000)
    float* out = (float*)d_out;                // (32, 26)

    char* ws = (char*)d_ws;
    u32* offw = (u32*)(ws + OFF_OFFW);
    u32* idb  = (u32*)(ws + OFF_IDB);
    u32* lvb  = (u32*)(ws + OFF_LVB);
    u32* part = (u32*)(ws + OFF_P8);

    size_t avail = ws_size > OFF_P8 ? ws_size - OFF_P8 : 0;
    const bool fast = avail >= (size_t)NCH * SLOT_BYTES;   // always true @256MiB

    dim3 g1(10, PK_ROWS);                      // 7250 blocks
    k_pack<<<g1, 256, 0, stream>>>(x, idw, lvw, idb, lvb, offw, out);

    if (fast) {
        dim3 g2(NTILE, 8, NCH);                // 1040 single-wave blocks
        k_bind_t<CHUNK><<<g2, 64, 0, stream>>>(idb, lvb, offw, part);
        dim3 g3(10, BATCH);                    // 320 blocks
        k_encl_t<NCH><<<g3, 256, 0, stream>>>(part, W, out);
    } else {
        int nch = (int)(avail / SLOT_BYTES);
        if (nch < 1) nch = 1;
        int chunk = (SPAD + nch - 1) / nch;
        chunk = (chunk + 1) & ~1;
        if (chunk > 62) chunk = 62;            // 6-plane CSA capacity bound
        nch = (SPAD + chunk - 1) / chunk;
        dim3 g2(NTILE, 8, nch);
        k_bind_g<<<g2, 64, 0, stream>>>(idb, lvb, offw, part, chunk);
        dim3 g3(10, BATCH);
        k_encl_g<<<g3, 256, 0, stream>>>(part, W, out, nch);
    }
}